// Round 2
// baseline (56328.577 us; speedup 1.0000x reference)
//
#include <hip/hip_runtime.h>
#include <cstdint>

#define NWG   128        // persistent workgroups (<= 256 CUs -> always co-resident)
#define BLK   256
#define HDIM  1024
#define DDIM  300
#define STEPS 8192       // U*L
#define NSAVE 64
#define SPIN_CAP 20000   // bounded spin: deadlock => fast wrong answer, not GPU hang

typedef unsigned long long u64;
typedef unsigned int u32;

// cross-step state in __device__ globals (no reliance on ws_size)
// g_hv[b][i] = (tag<<32) | float_bits(h[i]); tag = step t, buffer b = t&1
__device__ __align__(16) u64   g_hv[2][HDIM];
__device__ __align__(16) float g_hs[NSAVE][HDIM];

__device__ __forceinline__ float dot4(const float4 a, const float4 b) {
  return a.x * b.x + a.y * b.y + a.z * b.z + a.w * b.w;
}

__global__ void init_kernel() {
  const int i = blockIdx.x * blockDim.x + threadIdx.x;
  if (i < 2 * HDIM) ((u64*)g_hv)[i] = 0ULL;   // tag 0 never matches t>=1
}

__global__ __launch_bounds__(BLK, 1) void gru_kernel(
    const int* __restrict__ tokens, const float* __restrict__ emb,
    const float* __restrict__ Wih, const float* __restrict__ Whh,
    const float* __restrict__ bih, const float* __restrict__ bhh) {
  const int tid  = threadIdx.x;
  const int wg   = blockIdx.x;
  const int wave = tid >> 6;
  const int lane = tid & 63;
  // each wave owns 2 h-outputs; wg owns 8; 128 wgs cover 1024
  const int iA = wg * 8 + wave * 2;
  const int iB = iA + 1;

  const int rows[6] = { iA, HDIM + iA, 2 * HDIM + iA, iB, HDIM + iB, 2 * HDIM + iB };

  // W_hh fragments in registers: lane covers k = 256*c + 4*lane .. +3
  float4 whh[6][4];
#pragma unroll
  for (int d = 0; d < 6; ++d)
#pragma unroll
    for (int c = 0; c < 4; ++c)
      whh[d][c] = *(const float4*)(Whh + (size_t)rows[d] * HDIM + 256 * c + 4 * lane);

  // W_ih fragments: lane covers k = 64*j + lane (j=0..3) and 256+lane (lane<44)
  float wih[6][5];
#pragma unroll
  for (int d = 0; d < 6; ++d) {
#pragma unroll
    for (int j = 0; j < 4; ++j)
      wih[d][j] = Wih[(size_t)rows[d] * DDIM + 64 * j + lane];
    wih[d][4] = (lane < 44) ? Wih[(size_t)rows[d] * DDIM + 256 + lane] : 0.f;
  }
  // clamped in-bounds column for the 5th x element (value is masked by wih[.][4]==0)
  const int xcol4 = (256 + lane < DDIM) ? (256 + lane) : (DDIM - 1);

  const float cbrA = bih[iA] + bhh[iA];
  const float cbzA = bih[HDIM + iA] + bhh[HDIM + iA];
  const float binA = bih[2 * HDIM + iA];
  const float bhnA = bhh[2 * HDIM + iA];
  const float cbrB = bih[iB] + bhh[iB];
  const float cbzB = bih[HDIM + iB] + bhh[HDIM + iB];
  const float binB = bih[2 * HDIM + iB];
  const float bhnB = bhh[2 * HDIM + iB];

  // per-wave private x prefetch (no LDS, no barriers anywhere in the loop)
  auto loadrow = [&](int r, float* xv) {
    const int tok = tokens[r];
    const float* p = emb + (size_t)tok * DDIM;
    xv[0] = p[lane];       xv[1] = p[64 + lane];
    xv[2] = p[128 + lane]; xv[3] = p[192 + lane];
    xv[4] = p[xcol4];
  };

  float gxp[4], gxn[2];
  auto gxcalc = [&](const float* xv) {
    float s0 = 0.f, s1 = 0.f, s2 = 0.f, s3 = 0.f, s4 = 0.f, s5 = 0.f;
#pragma unroll
    for (int j = 0; j < 5; ++j) {
      s0 += wih[0][j] * xv[j];
      s1 += wih[1][j] * xv[j];
      s2 += wih[2][j] * xv[j];
      s3 += wih[3][j] * xv[j];
      s4 += wih[4][j] * xv[j];
      s5 += wih[5][j] * xv[j];
    }
    gxp[0] = s0; gxp[1] = s1; gxn[0] = s2;
    gxp[2] = s3; gxp[3] = s4; gxn[1] = s5;
  };

  // prologue: gx for step 1 (x row 0); xa = row 1; xb = row 2 (in flight)
  float xa[5], xb[5], x0[5];
  loadrow(0, x0);
  gxcalc(x0);
  loadrow(1, xa);
  loadrow(2, xb);

  float4 hc[4];
#pragma unroll
  for (int c = 0; c < 4; ++c) hc[c] = make_float4(0.f, 0.f, 0.f, 0.f);
  float hprevA = 0.f, hprevB = 0.f;

  for (int t = 1; t <= STEPS; ++t) {
    // ---- gh dots (gx r/z partials pre-merged into accumulators) ----
    float acc[8];
    acc[0] = gxp[0]; acc[1] = gxp[1]; acc[2] = 0.f;
    acc[3] = gxp[2]; acc[4] = gxp[3]; acc[5] = 0.f;
    acc[6] = gxn[0]; acc[7] = gxn[1];
#pragma unroll
    for (int c = 0; c < 4; ++c) {
      acc[0] += dot4(whh[0][c], hc[c]);
      acc[1] += dot4(whh[1][c], hc[c]);
      acc[2] += dot4(whh[2][c], hc[c]);
      acc[3] += dot4(whh[3][c], hc[c]);
      acc[4] += dot4(whh[4][c], hc[c]);
      acc[5] += dot4(whh[5][c], hc[c]);
    }
    // ---- wave all-reduce of 8 partial sums ----
#pragma unroll
    for (int m = 1; m < 64; m <<= 1) {
#pragma unroll
      for (int k = 0; k < 8; ++k) acc[k] += __shfl_xor(acc[k], m, 64);
    }
    // ---- gates (redundant across lanes; SIMD anyway) ----
    const float rA = 1.f / (1.f + expf(-(acc[0] + cbrA)));
    const float zA = 1.f / (1.f + expf(-(acc[1] + cbzA)));
    const float nA = tanhf(acc[6] + binA + rA * (acc[2] + bhnA));
    const float hA = (1.f - zA) * nA + zA * hprevA;
    const float rB = 1.f / (1.f + expf(-(acc[3] + cbrB)));
    const float zB = 1.f / (1.f + expf(-(acc[4] + cbzB)));
    const float nB = tanhf(acc[7] + binB + rB * (acc[5] + bhnB));
    const float hB = (1.f - zB) * nB + zB * hprevB;
    hprevA = hA; hprevB = hB;

    // ---- publish tagged values (8B agent-scope atomics -> LLC) ----
    if (lane == 0) {
      u64* hb = g_hv[t & 1];
      const u64 tagbase = ((u64)(u32)t) << 32;
      __hip_atomic_store(hb + iA, tagbase | (u64)__float_as_uint(hA),
                         __ATOMIC_RELAXED, __HIP_MEMORY_SCOPE_AGENT);
      __hip_atomic_store(hb + iB, tagbase | (u64)__float_as_uint(hB),
                         __ATOMIC_RELAXED, __HIP_MEMORY_SCOPE_AGENT);
      if ((t & 127) == 0) {               // t = 128,256,...,8192 -> slots 0..63
        __hip_atomic_store(&g_hs[(t >> 7) - 1][iA], hA,
                           __ATOMIC_RELAXED, __HIP_MEMORY_SCOPE_AGENT);
        __hip_atomic_store(&g_hs[(t >> 7) - 1][iB], hB,
                           __ATOMIC_RELAXED, __HIP_MEMORY_SCOPE_AGENT);
      }
    }

    if (t < STEPS) {
      // ---- overlap: gx partials for step t+1 (x row t, in xa) + shift prefetch ----
      gxcalc(xa);
#pragma unroll
      for (int j = 0; j < 5; ++j) xa[j] = xb[j];
      int r = t + 2; if (r > STEPS - 1) r = STEPS - 1;
      loadrow(r, xb);

      // ---- poll h_t: reload all 1024 tagged values, retry stale ones ----
      const u64* hb = g_hv[t & 1];
      const u32 want = (u32)t;
      u64 v[4][4];
#pragma unroll
      for (int c = 0; c < 4; ++c)
#pragma unroll
        for (int j = 0; j < 4; ++j)
          v[c][j] = __hip_atomic_load(hb + 256 * c + 4 * lane + j,
                                      __ATOMIC_RELAXED, __HIP_MEMORY_SCOPE_AGENT);
      int guard = 0;
      bool again = true;
      while (again && guard++ < SPIN_CAP) {
        again = false;
#pragma unroll
        for (int c = 0; c < 4; ++c)
#pragma unroll
          for (int j = 0; j < 4; ++j)
            if ((u32)(v[c][j] >> 32) != want) {
              again = true;
              v[c][j] = __hip_atomic_load(hb + 256 * c + 4 * lane + j,
                                          __ATOMIC_RELAXED, __HIP_MEMORY_SCOPE_AGENT);
            }
      }
#pragma unroll
      for (int c = 0; c < 4; ++c) {
        hc[c].x = __uint_as_float((u32)v[c][0]);
        hc[c].y = __uint_as_float((u32)v[c][1]);
        hc[c].z = __uint_as_float((u32)v[c][2]);
        hc[c].w = __uint_as_float((u32)v[c][3]);
      }
    }
  }
}

__global__ void out_kernel(const float* __restrict__ Wout, const float* __restrict__ bout,
                           float* __restrict__ out) {
  const int u = blockIdx.x;      // 64 blocks
  const int lane = threadIdx.x;  // 64 threads
  float4 hv[4];
#pragma unroll
  for (int c = 0; c < 4; ++c)
    hv[c] = *(const float4*)(g_hs[u] + 256 * c + 4 * lane);
  float acc[7];
#pragma unroll
  for (int o = 0; o < 7; ++o) {
    float s = 0.f;
#pragma unroll
    for (int c = 0; c < 4; ++c) {
      float4 w = *(const float4*)(Wout + (size_t)o * HDIM + 256 * c + 4 * lane);
      s += dot4(w, hv[c]);
    }
    acc[o] = s;
  }
#pragma unroll
  for (int m = 1; m < 64; m <<= 1) {
#pragma unroll
    for (int o = 0; o < 7; ++o) acc[o] += __shfl_xor(acc[o], m, 64);
  }
  if (lane == 0) {
#pragma unroll
    for (int o = 0; o < 7; ++o) out[u * 7 + o] = acc[o] + bout[o];
  }
}

extern "C" void kernel_launch(void* const* d_in, const int* in_sizes, int n_in,
                              void* d_out, int out_size, void* d_ws, size_t ws_size,
                              hipStream_t stream) {
  const int*   tokens = (const int*)d_in[0];
  const float* emb    = (const float*)d_in[1];
  const float* Wih    = (const float*)d_in[2];
  const float* Whh    = (const float*)d_in[3];
  const float* bihp   = (const float*)d_in[4];
  const float* bhhp   = (const float*)d_in[5];
  const float* Wout   = (const float*)d_in[6];
  const float* boutp  = (const float*)d_in[7];
  float* out = (float*)d_out;
  (void)d_ws; (void)ws_size; (void)in_sizes; (void)n_in; (void)out_size;

  init_kernel<<<8, 256, 0, stream>>>();
  gru_kernel<<<NWG, BLK, 0, stream>>>(tokens, emb, Wih, Whh, bihp, bhhp);
  out_kernel<<<64, 64, 0, stream>>>(Wout, boutp, out);
}

// Round 4
// 37337.946 us; speedup vs baseline: 1.5086x; 1.5086x over previous
//
#include <hip/hip_runtime.h>
#include <cstdint>

#define NWG   128        // persistent workgroups (<= 256 CUs -> always co-resident)
#define BLK   512        // 8 waves; each wave owns ONE h-output
#define HDIM  1024
#define DDIM  300
#define STEPS 8192       // U*L
#define NSAVE 64
#define SPIN_CAP 20000   // bounded spin: deadlock => fast wrong answer, not GPU hang

typedef unsigned long long u64;
typedef unsigned int u32;

// cross-step state in __device__ globals
// g_hv[b][i] = (tag<<32) | float_bits(h[i]); tag = step t, buffer b = t&1
__device__ __align__(16) u64   g_hv[2][HDIM];
__device__ __align__(16) float g_hs[NSAVE][HDIM];

__device__ __forceinline__ float dot4(const float4 a, const float4 b) {
  return a.x * b.x + a.y * b.y + a.z * b.z + a.w * b.w;
}

__global__ void init_kernel() {
  const int i = blockIdx.x * blockDim.x + threadIdx.x;
  if (i < 2 * HDIM) ((u64*)g_hv)[i] = 0ULL;   // tag 0 never matches t>=1
}

__global__ __launch_bounds__(BLK, 1) void gru_kernel(
    const int* __restrict__ tokens, const float* __restrict__ emb,
    const float* __restrict__ Wih, const float* __restrict__ Whh,
    const float* __restrict__ bih, const float* __restrict__ bhh) {
  const int tid  = threadIdx.x;
  const int wg   = blockIdx.x;
  const int wave = tid >> 6;
  const int lane = tid & 63;
  const int io   = wg * 8 + wave;          // owned h-output index (0..1023)

  const int rows[3] = { io, HDIM + io, 2 * HDIM + io };

  __shared__ __align__(16) float lds_h[2][HDIM];   // double-buffered h (8 KB)

  // W_hh rows in registers: lane covers k = 256*c + 4*lane .. +3  (48 VGPR)
  float4 whh[3][4];
#pragma unroll
  for (int d = 0; d < 3; ++d)
#pragma unroll
    for (int c = 0; c < 4; ++c)
      whh[d][c] = *(const float4*)(Whh + (size_t)rows[d] * HDIM + 256 * c + 4 * lane);

  // W_ih rows: lane covers k = 64*j + lane (j=0..3) and 256+lane (lane<44)
  float wih[3][5];
#pragma unroll
  for (int d = 0; d < 3; ++d) {
#pragma unroll
    for (int j = 0; j < 4; ++j)
      wih[d][j] = Wih[(size_t)rows[d] * DDIM + 64 * j + lane];
    wih[d][4] = (lane < 44) ? Wih[(size_t)rows[d] * DDIM + 256 + lane] : 0.f;
  }
  const int xcol4 = (256 + lane < DDIM) ? (256 + lane) : (DDIM - 1);

  const float cbr = bih[io] + bhh[io];
  const float cbz = bih[HDIM + io] + bhh[HDIM + io];
  const float bin = bih[2 * HDIM + io];
  const float bhn = bhh[2 * HDIM + io];

  // per-wave private x prefetch (no cross-wave coupling)
  auto loadrow = [&](int r, float* xv) {
    const int tok = tokens[r];
    const float* p = emb + (size_t)tok * DDIM;
    xv[0] = p[lane];       xv[1] = p[64 + lane];
    xv[2] = p[128 + lane]; xv[3] = p[192 + lane];
    xv[4] = p[xcol4];
  };

  float gxr, gxz, gxn;
  auto gxcalc = [&](const float* xv) {
    float s0 = 0.f, s1 = 0.f, s2 = 0.f;
#pragma unroll
    for (int j = 0; j < 5; ++j) {
      s0 += wih[0][j] * xv[j];
      s1 += wih[1][j] * xv[j];
      s2 += wih[2][j] * xv[j];
    }
    gxr = s0; gxz = s1; gxn = s2;
  };

  float xa[5], xb[5], x0[5];
  loadrow(0, x0);
  gxcalc(x0);
  loadrow(1, xa);
  loadrow(2, xb);

  float4 hc[4];
#pragma unroll
  for (int c = 0; c < 4; ++c) hc[c] = make_float4(0.f, 0.f, 0.f, 0.f);
  float hprev = 0.f;

  const int seg = (wave + wg) & 7;          // this wave's 128-value poll segment

  for (int t = 1; t <= STEPS; ++t) {
    // ---- gh dots (gx r/z merged into accumulators) ----
    float acc0 = gxr, acc1 = gxz, acc2 = 0.f, acc3 = gxn;
#pragma unroll
    for (int c = 0; c < 4; ++c) {
      acc0 += dot4(whh[0][c], hc[c]);
      acc1 += dot4(whh[1][c], hc[c]);
      acc2 += dot4(whh[2][c], hc[c]);
    }
    // ---- wave all-reduce of 4 partial sums ----
#pragma unroll
    for (int m = 1; m < 64; m <<= 1) {
      acc0 += __shfl_xor(acc0, m, 64);
      acc1 += __shfl_xor(acc1, m, 64);
      acc2 += __shfl_xor(acc2, m, 64);
      acc3 += __shfl_xor(acc3, m, 64);
    }
    // ---- gates (redundant across lanes) ----
    const float r = 1.f / (1.f + expf(-(acc0 + cbr)));
    const float z = 1.f / (1.f + expf(-(acc1 + cbz)));
    const float n = tanhf(acc3 + bin + r * (acc2 + bhn));
    const float h = (1.f - z) * n + z * hprev;
    hprev = h;

    // ---- publish tagged value (8B agent-scope atomic -> LLC) ----
    if (lane == 0) {
      __hip_atomic_store(&g_hv[t & 1][io],
                         (((u64)(u32)t) << 32) | (u64)__float_as_uint(h),
                         __ATOMIC_RELAXED, __HIP_MEMORY_SCOPE_AGENT);
      if ((t & 127) == 0)
        __hip_atomic_store(&g_hs[(t >> 7) - 1][io], h,
                           __ATOMIC_RELAXED, __HIP_MEMORY_SCOPE_AGENT);
    }

    if (t < STEPS) {
      // ---- overlap: gx for step t+1 + shift prefetch ----
      gxcalc(xa);
#pragma unroll
      for (int j = 0; j < 5; ++j) xa[j] = xb[j];
      int rr = t + 2; if (rr > STEPS - 1) rr = STEPS - 1;
      loadrow(rr, xb);

      // ---- poll own 128-value segment of h_t (2 u64 per lane) ----
      const u64* hb = g_hv[t & 1] + 128 * seg;
      const u32 want = (u32)t;
      u64 v0 = __hip_atomic_load(hb + 2 * lane + 0, __ATOMIC_RELAXED, __HIP_MEMORY_SCOPE_AGENT);
      u64 v1 = __hip_atomic_load(hb + 2 * lane + 1, __ATOMIC_RELAXED, __HIP_MEMORY_SCOPE_AGENT);
      int guard = 0;
      while (((u32)(v0 >> 32) != want || (u32)(v1 >> 32) != want) && guard++ < SPIN_CAP) {
        __builtin_amdgcn_s_sleep(1);   // backoff: don't hammer the LLC lines
        if ((u32)(v0 >> 32) != want)
          v0 = __hip_atomic_load(hb + 2 * lane + 0, __ATOMIC_RELAXED, __HIP_MEMORY_SCOPE_AGENT);
        if ((u32)(v1 >> 32) != want)
          v1 = __hip_atomic_load(hb + 2 * lane + 1, __ATOMIC_RELAXED, __HIP_MEMORY_SCOPE_AGENT);
      }
      // ---- share via LDS, one barrier, read full h ----
      *(float2*)&lds_h[t & 1][128 * seg + 2 * lane] =
          make_float2(__uint_as_float((u32)v0), __uint_as_float((u32)v1));
      __syncthreads();
#pragma unroll
      for (int c = 0; c < 4; ++c)
        hc[c] = *(const float4*)&lds_h[t & 1][256 * c + 4 * lane];
    }
  }
}

__global__ void out_kernel(const float* __restrict__ Wout, const float* __restrict__ bout,
                           float* __restrict__ out) {
  const int u = blockIdx.x;      // 64 blocks
  const int lane = threadIdx.x;  // 64 threads
  float4 hv[4];
#pragma unroll
  for (int c = 0; c < 4; ++c)
    hv[c] = *(const float4*)(g_hs[u] + 256 * c + 4 * lane);
  float acc[7];
#pragma unroll
  for (int o = 0; o < 7; ++o) {
    float s = 0.f;
#pragma unroll
    for (int c = 0; c < 4; ++c) {
      float4 w = *(const float4*)(Wout + (size_t)o * HDIM + 256 * c + 4 * lane);
      s += dot4(w, hv[c]);
    }
    acc[o] = s;
  }
#pragma unroll
  for (int m = 1; m < 64; m <<= 1) {
#pragma unroll
    for (int o = 0; o < 7; ++o) acc[o] += __shfl_xor(acc[o], m, 64);
  }
  if (lane == 0) {
#pragma unroll
    for (int o = 0; o < 7; ++o) out[u * 7 + o] = acc[o] + bout[o];
  }
}

extern "C" void kernel_launch(void* const* d_in, const int* in_sizes, int n_in,
                              void* d_out, int out_size, void* d_ws, size_t ws_size,
                              hipStream_t stream) {
  const int*   tokens = (const int*)d_in[0];
  const float* emb    = (const float*)d_in[1];
  const float* Wih    = (const float*)d_in[2];
  const float* Whh    = (const float*)d_in[3];
  const float* bihp   = (const float*)d_in[4];
  const float* bhhp   = (const float*)d_in[5];
  const float* Wout   = (const float*)d_in[6];
  const float* boutp  = (const float*)d_in[7];
  float* out = (float*)d_out;
  (void)d_ws; (void)ws_size; (void)in_sizes; (void)n_in; (void)out_size;

  init_kernel<<<8, 256, 0, stream>>>();
  gru_kernel<<<NWG, BLK, 0, stream>>>(tokens, emb, Wih, Whh, bihp, bhhp);
  out_kernel<<<64, 64, 0, stream>>>(Wout, boutp, out);
}